// Round 4
// 31760.577 us; speedup vs baseline: 1.1504x; 1.1504x over previous
//
#include <hip/hip_runtime.h>
#include <hip/hip_cooperative_groups.h>

namespace cg = cooperative_groups;

#define Bq 512
#define Lq 512
#define Iq 32
#define Hq 512
#define DTc 0.042f

typedef __attribute__((ext_vector_type(8))) short short8v;    // bf16x8 fragment
typedef __attribute__((ext_vector_type(4))) float float4v;    // fp32 accumulator
typedef __attribute__((ext_vector_type(4))) unsigned short ushort4v;

__device__ inline unsigned short f2bf(float f) {
    union { float f; unsigned u; } v; v.f = f;
    unsigned u = v.u;
    unsigned r = (u + 0x7FFFu + ((u >> 16) & 1u)) >> 16;  // RNE
    return (unsigned short)r;
}

__device__ inline float tanh_fast(float x) {
    float e = __expf(2.0f * x);
    return 1.0f - 2.0f / (e + 1.0f);
}

// 64 blocks x 1024 threads. Same total lanes (65536) and same per-wave inner
// loop as the proven 256x256 kernel -> bitwise-identical outputs. The point:
// cg::grid.sync() cost is dominated by serialized block-arrival atomics on one
// counter (256 arrivals x ~300cy IF$ RMW ~= the measured 35us/sync). 64 blocks
// cuts arrivals 4x; 16 waves/CU also hides post-sync IF$ refetch latency.
__global__ __launch_bounds__(1024) void coesn_kernel(
    const float* __restrict__ x,     // (B, L, I)
    const float* __restrict__ x2h,   // (I, H)
    const float* __restrict__ h2h,   // (H, H)
    const float* __restrict__ h2hT,  // (H, H)
    const float* __restrict__ bias,  // (H)
    const float* __restrict__ gamma, // (H)
    const float* __restrict__ eps,   // (H)
    float* __restrict__ out,         // (B,L,H) then (B,H)
    unsigned short* __restrict__ ws)
{
    // workspace layout (ushort elements) -- identical to the proven kernel
    unsigned short* hy_bf   = ws;                  // (B,H) row-major bf16
    unsigned short* T_cm    = ws + 512 * 512;      // (H,B): T_cm[j][k] = T[k][j]
    unsigned short* h2h_cm  = ws + 2 * 512 * 512;  // (H,H): h2h_cm[j][m] = h2h[m][j]
    unsigned short* h2hT_bf = ws + 3 * 512 * 512;  // (H,H) row-major bf16
    float* x2h_cm = (float*)(ws + 4 * 512 * 512);  // (H,I): x2h_cm[j][i] = x2h[i][j]

    const int tid  = threadIdx.x;
    const int wg   = blockIdx.x;
    const int gtid = wg * 1024 + tid;              // 0..65535

    // ---------------- setup (ws is poison-filled before every launch) -----------
    for (int idx = gtid; idx < 512 * 512; idx += 65536) {
        int j = idx >> 9, m = idx & 511;
        h2h_cm[idx]  = f2bf(h2h[m * 512 + j]);
        h2hT_bf[idx] = f2bf(h2hT[idx]);
        hy_bf[idx]   = 0;
    }
    for (int idx = gtid; idx < 512 * 32; idx += 65536) {
        int j = idx >> 5, i = idx & 31;
        x2h_cm[idx] = x2h[i * 512 + j];
    }

    cg::grid_group grid = cg::this_grid();
    grid.sync();

    // ---------------- tile / lane geometry --------------------------------------
    const int rt = wg >> 3, ct = wg & 7;       // 8x8 grid of 64x64 tiles
    const int R = rt * 64, C = ct * 64;
    const int w    = tid >> 6;                 // wave 0..15
    const int lane = tid & 63;
    const int sr = w >> 2, sc = w & 3;         // 4x4 16x16 sub-tiles in the 64x64
    const int q = lane >> 4, n = lane & 15;
    const int arow  = R + sr * 16 + n;         // A-fragment row (m = lane&15)
    const int ocol  = C + sc * 16 + n;         // output column (n = lane&15)
    const int crow0 = R + sr * 16 + q * 4;     // C/D rows base (row = q*4 + reg)

    const float gamma_v = gamma[ocol];
    const float eps_v   = eps[ocol];
    const float bias_v  = bias[ocol];

    // x2h column for U (column fixed per lane for the whole run)
    float xw[32];
#pragma unroll
    for (int i = 0; i < 32; i++) xw[i] = x2h_cm[ocol * 32 + i];

    // persistent per-lane state (tile ownership fixed across steps)
    float hy_r[4] = {0.f, 0.f, 0.f, 0.f};
    float hz_r[4] = {0.f, 0.f, 0.f, 0.f};

    const unsigned short* Arow1 = hy_bf + arow * 512;    // phase-1 A base
    const unsigned short* Brow1 = h2h_cm + ocol * 512;   // phase-1 B base
    const unsigned short* Arow2 = h2hT_bf + arow * 512;  // phase-2 A base
    const unsigned short* Brow2 = T_cm + ocol * 512;     // phase-2 B base

    for (int t = 0; t < Lq; t++) {
        // ---- U = xt @ x2h (independent of the recurrence; issued here so the
        //      loads overlap the post-sync phase-1 operand refetch latency)
        float u_r[4];
#pragma unroll
        for (int r = 0; r < 4; r++) {
            const int brow = crow0 + r;
            const float* xr = x + (size_t)brow * (Lq * Iq) + t * Iq;
            float u = 0.f;
#pragma unroll
            for (int i = 0; i < 32; i++) u += xr[i] * xw[i];  // wave-broadcast loads
            u_r[r] = u;
        }

        // ---------- phase 1: T = tanh(hy @ h2h + bias), stored column-major bf16 --
        float4v acc = {0.f, 0.f, 0.f, 0.f};
#pragma unroll
        for (int ks = 0; ks < 16; ks++) {
            const int k0 = ks * 32 + q * 8;
            short8v a = *(const short8v*)(Arow1 + k0);
            short8v b = *(const short8v*)(Brow1 + k0);
            acc = __builtin_amdgcn_mfma_f32_16x16x32_bf16(a, b, acc, 0, 0, 0);
        }
        ushort4v tv;
#pragma unroll
        for (int r = 0; r < 4; r++) tv[r] = f2bf(tanh_fast(acc[r] + bias_v));
        *(ushort4v*)(T_cm + ocol * 512 + crow0) = tv;

        grid.sync();

        // ---------- phase 2: V = h2h_T @ T; state update ---------------------------
        float4v vacc = {0.f, 0.f, 0.f, 0.f};
#pragma unroll
        for (int ks = 0; ks < 16; ks++) {
            const int k0 = ks * 32 + q * 8;
            short8v a = *(const short8v*)(Arow2 + k0);
            short8v b = *(const short8v*)(Brow2 + k0);
            vacc = __builtin_amdgcn_mfma_f32_16x16x32_bf16(a, b, vacc, 0, 0, 0);
        }

#pragma unroll
        for (int r = 0; r < 4; r++) {
            float hz = hz_r[r] + DTc * (u_r[r] - vacc[r] - gamma_v * hy_r[r] - eps_v * hz_r[r]);
            float hy = hy_r[r] + DTc * hz;
            hz_r[r] = hz;
            hy_r[r] = hy;

            const int brow = crow0 + r;
            out[(size_t)brow * (Lq * Hq) + (size_t)t * Hq + ocol] = hy;
            hy_bf[brow * 512 + ocol] = f2bf(hy);
        }

        grid.sync();
    }

    // final hy (second output), concatenated after (B,L,H)
#pragma unroll
    for (int r = 0; r < 4; r++) {
        out[(size_t)Bq * Lq * Hq + (size_t)(crow0 + r) * Hq + ocol] = hy_r[r];
    }
}

extern "C" void kernel_launch(void* const* d_in, const int* in_sizes, int n_in,
                              void* d_out, int out_size, void* d_ws, size_t ws_size,
                              hipStream_t stream) {
    const float* x     = (const float*)d_in[0];
    const float* x2h   = (const float*)d_in[1];
    const float* h2h   = (const float*)d_in[2];
    const float* h2hT  = (const float*)d_in[3];
    const float* bias  = (const float*)d_in[4];
    const float* gamma = (const float*)d_in[5];
    const float* eps   = (const float*)d_in[6];
    float* out = (float*)d_out;
    unsigned short* ws = (unsigned short*)d_ws;

    void* args[] = {&x, &x2h, &h2h, &h2hT, &bias, &gamma, &eps, &out, &ws};
    hipLaunchCooperativeKernel((void*)coesn_kernel, dim3(64), dim3(1024), args, 0, stream);
}